// Round 1
// baseline (332.241 us; speedup 1.0000x reference)
//
#include <hip/hip_runtime.h>

// Problem constants (fixed by the reference).
#define BB 32
#define KK 8192
#define EE 128
#define HH 128
#define CH 16                     // K-chunks per batch -> B*CH = 512 blocks
#define TOK_PER_BLK (KK / CH)     // 512 tokens per block
#define STRIP 32                  // tokens per LDS strip
#define NSTRIP (TOK_PER_BLK / STRIP)
#define ZSTR 136                  // LDS row stride in shorts (128 + 8 pad -> 16B-aligned, bank-friendly)

typedef short bf16x8 __attribute__((ext_vector_type(8)));
typedef float f32x4  __attribute__((ext_vector_type(4)));

static __device__ __forceinline__ unsigned short f2bf(float x) {
    union { float f; unsigned u; } v; v.f = x;
    unsigned u = v.u;
    u += 0x7FFFu + ((u >> 16) & 1u);   // round-to-nearest-even
    return (unsigned short)(u >> 16);
}

// Load 8 contiguous fp32 and convert to a bf16 MFMA fragment (16B).
static __device__ __forceinline__ bf16x8 load8_bf16(const float* __restrict__ p) {
    const float4 a = ((const float4*)p)[0];
    const float4 b = ((const float4*)p)[1];
    bf16x8 r;
    r[0] = (short)f2bf(a.x); r[1] = (short)f2bf(a.y);
    r[2] = (short)f2bf(a.z); r[3] = (short)f2bf(a.w);
    r[4] = (short)f2bf(b.x); r[5] = (short)f2bf(b.y);
    r[6] = (short)f2bf(b.z); r[7] = (short)f2bf(b.w);
    return r;
}

// ---------------------------------------------------------------------------
// Phase 1: per-chunk partial column-max of z @ M2^T  (no bias; added in reduce)
// grid = B*CH blocks of 256 threads (4 waves).
// ---------------------------------------------------------------------------
__global__ __launch_bounds__(256, 2)
void pool_partial(const float* __restrict__ z, const float* __restrict__ M2w,
                  float* __restrict__ part) {
    __shared__ unsigned short zl[STRIP * ZSTR];
    __shared__ float red[2][EE];

    const int tid  = threadIdx.x;
    const int w    = tid >> 6, lane = tid & 63, q = lane >> 4, l16 = lane & 15;
    const int blk  = blockIdx.x;
    const int b    = blk >> 4, ch = blk & (CH - 1);
    const long tok0 = (long)b * KK + (long)ch * TOK_PER_BLK;

    const int ts = w & 1;       // token sub-strip (16 tokens)
    const int fh = w >> 1;      // feature half (4 tiles of 16 features)

    // M2 weight fragments in registers: f = (fh*4+ft)*16 + l16, k-block 0..3
    bf16x8 wf[4][4];
    for (int ft = 0; ft < 4; ++ft) {
        const int f = (fh * 4 + ft) * 16 + l16;
        for (int k = 0; k < 4; ++k)
            wf[ft][k] = load8_bf16(M2w + f * EE + k * 32 + q * 8);
    }

    float fmax[4] = {-3.0e38f, -3.0e38f, -3.0e38f, -3.0e38f};

    for (int s = 0; s < NSTRIP; ++s) {
        // stage 32 tokens x 128 fp32 -> bf16 LDS (4 float4 per thread)
        for (int i = 0; i < 4; ++i) {
            const int idx = i * 256 + tid;          // 0..1023
            const int row = idx >> 5, c4 = idx & 31;
            const float4 v = ((const float4*)(z + (tok0 + s * STRIP + row) * EE))[c4];
            ushort4 o;
            o.x = f2bf(v.x); o.y = f2bf(v.y); o.z = f2bf(v.z); o.w = f2bf(v.w);
            *(ushort4*)&zl[row * ZSTR + c4 * 4] = o;
        }
        __syncthreads();

        f32x4 acc[4] = {};
        for (int k = 0; k < 4; ++k) {
            const bf16x8 a = *(const bf16x8*)&zl[(ts * 16 + l16) * ZSTR + k * 32 + q * 8];
            for (int ft = 0; ft < 4; ++ft)
                acc[ft] = __builtin_amdgcn_mfma_f32_16x16x32_bf16(a, wf[ft][k], acc[ft], 0, 0, 0);
        }
        for (int ft = 0; ft < 4; ++ft)
            for (int r = 0; r < 4; ++r)
                fmax[ft] = fmaxf(fmax[ft], acc[ft][r]);
        __syncthreads();   // before next strip overwrites zl
    }

    // reduce across the 4 row-groups (q) within the wave
    for (int ft = 0; ft < 4; ++ft) {
        float v = fmax[ft];
        v = fmaxf(v, __shfl_xor(v, 16, 64));
        v = fmaxf(v, __shfl_xor(v, 32, 64));
        fmax[ft] = v;
    }
    if (lane < 16) {
        for (int ft = 0; ft < 4; ++ft)
            red[ts][(fh * 4 + ft) * 16 + lane] = fmax[ft];
    }
    __syncthreads();
    if (tid < EE) {
        const float pm = fmaxf(red[0][tid], red[1][tid]);
        part[(size_t)blk * EE + tid] = pm;
    }
}

// ---------------------------------------------------------------------------
// Phase 1b: reduce partials over chunks, add M2 bias. grid = B, block = 128.
// ---------------------------------------------------------------------------
__global__ void pool_reduce(const float* __restrict__ part,
                            const float* __restrict__ M2b,
                            float* __restrict__ pooled) {
    const int b = blockIdx.x, f = threadIdx.x;
    float m = -3.0e38f;
    for (int ch = 0; ch < CH; ++ch)
        m = fmaxf(m, part[((size_t)(b * CH + ch)) * EE + f]);
    pooled[b * EE + f] = m + M2b[f];
}

// ---------------------------------------------------------------------------
// Phase 2: out = relu([z | relu(z@M1^T + b1 + pooled)] @ U^T + bU)
// grid = B*CH blocks of 256 threads (4 waves).
// ---------------------------------------------------------------------------
__global__ __launch_bounds__(256, 2)
void fused_main(const float* __restrict__ z,  const float* __restrict__ M1w,
                const float* __restrict__ M1b, const float* __restrict__ Uw,
                const float* __restrict__ Ub,  const float* __restrict__ pooled,
                float* __restrict__ out) {
    __shared__ unsigned short zl[STRIP * ZSTR];
    __shared__ unsigned short ml[STRIP * ZSTR];

    const int tid  = threadIdx.x;
    const int w    = tid >> 6, lane = tid & 63, q = lane >> 4, l16 = lane & 15;
    const int blk  = blockIdx.x;
    const int b    = blk >> 4, ch = blk & (CH - 1);
    const long tok0 = (long)b * KK + (long)ch * TOK_PER_BLK;

    const int ts = w & 1;    // token sub-strip
    const int fh = w >> 1;   // feature/h half (tiles fh*4 .. fh*4+3)

    // M1 weight fragments + fused bias (M1_b + pooled), per feature tile
    bf16x8 wf1[4][4];
    float  bp[4];
    for (int ft = 0; ft < 4; ++ft) {
        const int f = (fh * 4 + ft) * 16 + l16;
        for (int k = 0; k < 4; ++k)
            wf1[ft][k] = load8_bf16(M1w + f * EE + k * 32 + q * 8);
        bp[ft] = M1b[f] + pooled[b * EE + f];
    }
    // U weight fragments over K=256 (first 128 = z part, last 128 = m part)
    bf16x8 wfu[4][8];
    float  ub[4];
    for (int ht = 0; ht < 4; ++ht) {
        const int h = (fh * 4 + ht) * 16 + l16;
        for (int kk = 0; kk < 8; ++kk)
            wfu[ht][kk] = load8_bf16(Uw + h * (2 * EE) + kk * 32 + q * 8);
        ub[ht] = Ub[h];
    }

    for (int s = 0; s < NSTRIP; ++s) {
        // stage z strip
        for (int i = 0; i < 4; ++i) {
            const int idx = i * 256 + tid;
            const int row = idx >> 5, c4 = idx & 31;
            const float4 v = ((const float4*)(z + (tok0 + s * STRIP + row) * EE))[c4];
            ushort4 o;
            o.x = f2bf(v.x); o.y = f2bf(v.y); o.z = f2bf(v.z); o.w = f2bf(v.w);
            *(ushort4*)&zl[row * ZSTR + c4 * 4] = o;
        }
        __syncthreads();

        // step 1: m = relu(z @ M1^T + M1_b + pooled) -> bf16 LDS tile
        {
            f32x4 acc[4] = {};
            for (int k = 0; k < 4; ++k) {
                const bf16x8 a = *(const bf16x8*)&zl[(ts * 16 + l16) * ZSTR + k * 32 + q * 8];
                for (int ft = 0; ft < 4; ++ft)
                    acc[ft] = __builtin_amdgcn_mfma_f32_16x16x32_bf16(a, wf1[ft][k], acc[ft], 0, 0, 0);
            }
            for (int ft = 0; ft < 4; ++ft) {
                const int f = (fh * 4 + ft) * 16 + l16;
                for (int r = 0; r < 4; ++r) {
                    const float v = fmaxf(acc[ft][r] + bp[ft], 0.0f);
                    ml[(ts * 16 + q * 4 + r) * ZSTR + f] = f2bf(v);
                }
            }
        }
        __syncthreads();

        // step 2: out = relu([z | m] @ U^T + U_b)
        {
            f32x4 acc[4] = {};
            for (int kk = 0; kk < 8; ++kk) {
                bf16x8 a;
                if (kk < 4)
                    a = *(const bf16x8*)&zl[(ts * 16 + l16) * ZSTR + kk * 32 + q * 8];
                else
                    a = *(const bf16x8*)&ml[(ts * 16 + l16) * ZSTR + (kk - 4) * 32 + q * 8];
                for (int ht = 0; ht < 4; ++ht)
                    acc[ht] = __builtin_amdgcn_mfma_f32_16x16x32_bf16(a, wfu[ht][kk], acc[ht], 0, 0, 0);
            }
            for (int ht = 0; ht < 4; ++ht) {
                const int h = (fh * 4 + ht) * 16 + l16;
                for (int r = 0; r < 4; ++r) {
                    const float v = fmaxf(acc[ht][r] + ub[ht], 0.0f);
                    out[(tok0 + s * STRIP + ts * 16 + q * 4 + r) * HH + h] = v;
                }
            }
        }
        __syncthreads();   // before next strip overwrites zl/ml
    }
}

// ---------------------------------------------------------------------------
extern "C" void kernel_launch(void* const* d_in, const int* in_sizes, int n_in,
                              void* d_out, int out_size, void* d_ws, size_t ws_size,
                              hipStream_t stream) {
    const float* z   = (const float*)d_in[0];
    const float* M1w = (const float*)d_in[1];
    const float* M1b = (const float*)d_in[2];
    const float* M2w = (const float*)d_in[3];
    const float* M2b = (const float*)d_in[4];
    const float* Uw  = (const float*)d_in[5];
    const float* Ub  = (const float*)d_in[6];
    float* out = (float*)d_out;

    // workspace layout: [0, B*CH*E) partial maxes, then [.., +B*E) pooled
    float* part   = (float*)d_ws;
    float* pooled = part + (size_t)BB * CH * EE;

    hipLaunchKernelGGL(pool_partial, dim3(BB * CH), dim3(256), 0, stream, z, M2w, part);
    hipLaunchKernelGGL(pool_reduce,  dim3(BB),      dim3(EE),  0, stream, part, M2b, pooled);
    hipLaunchKernelGGL(fused_main,   dim3(BB * CH), dim3(256), 0, stream,
                       z, M1w, M1b, Uw, Ub, pooled, out);
}